// Round 2
// 20619.279 us; speedup vs baseline: 1.3666x; 1.3666x over previous
//
#include <hip/hip_runtime.h>
#include <hip/hip_bf16.h>
#include <stdint.h>

using bf16 = __hip_bfloat16;
typedef short bf16x8 __attribute__((ext_vector_type(8)));
typedef float f32x4 __attribute__((ext_vector_type(4)));

#define BB 64
#define LL 12
#define DD 768
#define HH 12
#define HDD 64
#define FFD 3072
#define NN 197
#define NPP 196
#define NCC 100
#define MROWS (BB * NN)      // 12608
#define MPAD  12672          // 99*128

__device__ __forceinline__ float bflo(uint32_t u) { return __uint_as_float(u << 16); }
__device__ __forceinline__ float bfhi(uint32_t u) { return __uint_as_float(u & 0xffff0000u); }
__device__ __forceinline__ uint32_t f2bf_bits(float f) {
    bf16 h = __float2bfloat16(f);           // RNE
    union { uint16_t u; bf16 b; } c; c.b = h;
    return (uint32_t)c.u;
}
__device__ __forceinline__ uint32_t pk2(float a, float b) { return f2bf_bits(a) | (f2bf_bits(b) << 16); }
__device__ __forceinline__ uint4 pack8(float4 a, float4 b) {
    uint4 r; r.x = pk2(a.x, a.y); r.y = pk2(a.z, a.w); r.z = pk2(b.x, b.y); r.w = pk2(b.z, b.w); return r;
}
// async global->LDS, 16B per lane; lds ptr must be wave-uniform base (+lane*16 by HW)
__device__ __forceinline__ void glds16(const void* g, void* l) {
    __builtin_amdgcn_global_load_lds((__attribute__((address_space(1))) void*)g,
                                     (__attribute__((address_space(3))) void*)l, 16, 0, 0);
}

// ---------------- fp32 -> bf16 weight conversion (RNE, identical to old in-GEMM pack8) ----------------
__global__ __launch_bounds__(256) void f2b_kernel(const float* __restrict__ s, bf16* __restrict__ d, int n8) {
    int i = blockIdx.x * 256 + threadIdx.x;
    if (i >= n8) return;
    const float4* sp = (const float4*)(s + (size_t)i * 8);
    *(uint4*)(d + (size_t)i * 8) = pack8(sp[0], sp[1]);
}

// ---------------- patchify: inputs fp32 [B,3,224,224] -> P bf16 [B*196, 768] (timm order) ----------------
__global__ __launch_bounds__(256) void patchify_kernel(const float* __restrict__ inp, bf16* __restrict__ P) {
    int i = blockIdx.x * 256 + threadIdx.x;             // 8 elements per thread
    const int total = NPP * BB * 96;
    if (i >= total) return;
    int c8 = i % 96;
    int r  = i / 96;
    int b = r / NPP, p = r % NPP;
    int ph = p / 14, pw = p % 14;
    int c = c8 * 8;
    int ch = c >> 8;
    int rem = c & 255;
    int ii = rem >> 4, jj = rem & 15;
    const float* src = inp + ((size_t)((b * 3 + ch) * 224 + ph * 16 + ii)) * 224 + pw * 16 + jj;
    float4 f0 = *(const float4*)src;
    float4 f1 = *(const float4*)(src + 4);
    *(uint4*)(P + (size_t)r * DD + c) = pack8(f0, f1);
}

// ---------------- GEMM: C[M,N] = A_bf16[M,K] @ W_bf16[N,K]^T + bias (+res)(+gelu) ----------------
// m97 structure: global_load_lds width=16 staging for A and B, 128x128 tile, BK=64, 2 barriers/K-step.
template<bool RES, bool GELU, bool OUTF32>
__global__ __launch_bounds__(256) void gemm_bb(
    const bf16* __restrict__ A, const bf16* __restrict__ W, const float* __restrict__ bias,
    const float* res, float* outf, bf16* outb, int M, int N, int K)
{
    __shared__ __align__(16) bf16 As[128 * 64];
    __shared__ __align__(16) bf16 Bs[128 * 64];
    const int t = threadIdx.x;
    const int lane = t & 63;
    const int wv = t >> 6;
    const int q15 = lane & 15, quad = lane >> 4;
    const int row0 = blockIdx.x * 128, col0 = blockIdx.y * 128;
    const int wm = (wv >> 1) * 64, wn = (wv & 1) * 64;

    f32x4 acc[4][4];
#pragma unroll
    for (int a = 0; a < 4; a++)
#pragma unroll
        for (int b2 = 0; b2 < 4; b2++) { f32x4 z = {0.f, 0.f, 0.f, 0.f}; acc[a][b2] = z; }

    const int sr = t >> 3;          // staging row within 32-row group
    const int sc = (t & 7) * 8;     // staging col (elements)
    const bf16* Ag = A + (size_t)(row0 + sr) * K + sc;
    const bf16* Wg = W + (size_t)(col0 + sr) * K + sc;
    bf16* lA = As + wv * 512;       // wave-uniform LDS base; lane i lands at +i*16B (linear order)
    bf16* lB = Bs + wv * 512;

    for (int kt = 0; kt < K; kt += 64) {
#pragma unroll
        for (int i = 0; i < 4; i++) {
            glds16(Ag + (size_t)(i * 32) * K + kt, lA + i * 2048);
            glds16(Wg + (size_t)(i * 32) * K + kt, lB + i * 2048);
        }
        __syncthreads();   // compiler drains vmcnt(0) before barrier: tile resident
#pragma unroll
        for (int k0 = 0; k0 < 64; k0 += 32) {
            bf16x8 af[4], bfv[4];
#pragma unroll
            for (int mi = 0; mi < 4; mi++)
                af[mi] = *(const bf16x8*)(As + (wm + mi * 16 + q15) * 64 + k0 + quad * 8);
#pragma unroll
            for (int ni = 0; ni < 4; ni++)
                bfv[ni] = *(const bf16x8*)(Bs + (wn + ni * 16 + q15) * 64 + k0 + quad * 8);
#pragma unroll
            for (int mi = 0; mi < 4; mi++)
#pragma unroll
                for (int ni = 0; ni < 4; ni++)
                    acc[mi][ni] = __builtin_amdgcn_mfma_f32_16x16x32_bf16(af[mi], bfv[ni], acc[mi][ni], 0, 0, 0);
        }
        __syncthreads();   // all waves done reading before next tile overwrites
    }

#pragma unroll
    for (int mi = 0; mi < 4; mi++) {
#pragma unroll
        for (int ni = 0; ni < 4; ni++) {
            const int c = col0 + wn + ni * 16 + q15;
            const float bv = bias[c];
#pragma unroll
            for (int r = 0; r < 4; r++) {
                const int row = row0 + wm + mi * 16 + quad * 4 + r;
                if (row < M) {
                    float v = acc[mi][ni][r] + bv;
                    if (RES) v += res[(size_t)row * N + c];
                    if (GELU) v = 0.5f * v * (1.0f + erff(v * 0.70710678118654752f));
                    if (OUTF32) outf[(size_t)row * N + c] = v;
                    else outb[(size_t)row * N + c] = __float2bfloat16(v);
                }
            }
        }
    }
}

// ---------------- assemble xb = concat(cls, patches) + pos (fp32 residual) ----------------
__global__ __launch_bounds__(256) void assemble_x0_kernel(const float* __restrict__ tmp,
    const float* __restrict__ cls, const float* __restrict__ pos, float* __restrict__ xb)
{
    size_t i = (size_t)blockIdx.x * 256 + threadIdx.x;
    if (i >= (size_t)MROWS * DD) return;
    int c = (int)(i % DD);
    int r = (int)(i / DD);
    int b = r / NN, tt = r % NN;
    float v;
    if (tt == 0) v = cls[c];
    else        v = tmp[(size_t)(b * NPP + tt - 1) * DD + c];
    v += pos[(size_t)tt * DD + c];
    xb[i] = v;
}

// ---------------- LayerNorm row kernel: fp32 in -> bf16 out, fp32 params ----------------
__global__ __launch_bounds__(256) void ln_kernel(const float* __restrict__ x, long long rstride,
    const float* __restrict__ sc, const float* __restrict__ bi, bf16* __restrict__ out)
{
    int r = blockIdx.x;
    const float* xr = x + (size_t)r * rstride;
    int t = threadIdx.x;
    float v0 = xr[t], v1 = xr[t + 256], v2 = xr[t + 512];
    __shared__ float r1[256], r2[256];
    r1[t] = v0 + v1 + v2;
    r2[t] = v0 * v0 + v1 * v1 + v2 * v2;
    __syncthreads();
    for (int o = 128; o > 0; o >>= 1) {
        if (t < o) { r1[t] += r1[t + o]; r2[t] += r2[t + o]; }
        __syncthreads();
    }
    float mu = r1[0] * (1.f / 768.f);
    float var = fmaxf(r2[0] * (1.f / 768.f) - mu * mu, 0.f);
    float rs = rsqrtf(var + 1e-6f);
    bf16* o_ = out + (size_t)r * DD;
    o_[t]       = __float2bfloat16((v0 - mu) * rs * sc[t]       + bi[t]);
    o_[t + 256] = __float2bfloat16((v1 - mu) * rs * sc[t + 256] + bi[t + 256]);
    o_[t + 512] = __float2bfloat16((v2 - mu) * rs * sc[t + 512] + bi[t + 512]);
}

// ---------------- attention (baseline scalar version, verbatim): one block per (b, head) ----------------
__global__ __launch_bounds__(256) void attn_kernel(const bf16* __restrict__ qkv,
    const bf16* __restrict__ pk, const bf16* __restrict__ pv,
    int n_extra, int pstride, bf16* __restrict__ out)
{
    const int bh = blockIdx.x;
    const int b = bh / HH, hh = bh % HH;
    const int Nk = NN + n_extra;
    __shared__ __align__(16) bf16 kl[217 * 64];
    __shared__ __align__(16) bf16 vl[217 * 64];
    const int t = threadIdx.x;
    for (int idx = t; idx < Nk * 8; idx += 256) {
        int j = idx >> 3, c = (idx & 7) * 8;
        const bf16 *ks, *vs;
        if (j < NN) {
            const bf16* base = qkv + ((size_t)(b * NN + j)) * 2304 + hh * 64 + c;
            ks = base + 768; vs = base + 1536;
        } else {
            size_t off = (size_t)(pstride ? b * pstride : 0) + (size_t)(j - NN) * DD + hh * 64 + c;
            ks = pk + off; vs = pv + off;
        }
        *(uint4*)(kl + j * 64 + c) = *(const uint4*)ks;
        *(uint4*)(vl + j * 64 + c) = *(const uint4*)vs;
    }
    __syncthreads();

    int row = (t < NN) ? t : (NN - 1);
    float qv[64];
    {
        const uint32_t* qs = (const uint32_t*)(qkv + ((size_t)(b * NN + row)) * 2304 + hh * 64);
#pragma unroll
        for (int d2 = 0; d2 < 32; d2++) {
            uint32_t u = qs[d2];
            qv[d2 * 2] = bflo(u); qv[d2 * 2 + 1] = bfhi(u);
        }
    }
    float acc[64];
#pragma unroll
    for (int d = 0; d < 64; d++) acc[d] = 0.f;
    float mx = -1e30f, l = 0.f;

    for (int j = 0; j < Nk; j++) {
        const uint32_t* kr = (const uint32_t*)(kl + j * 64);
        float s = 0.f;
#pragma unroll
        for (int d2 = 0; d2 < 32; d2++) {
            uint32_t u = kr[d2];
            s += qv[d2 * 2] * bflo(u) + qv[d2 * 2 + 1] * bfhi(u);
        }
        s *= 0.125f;
        if (s > mx) {
            float corr = __expf(mx - s);
            l *= corr;
#pragma unroll
            for (int d = 0; d < 64; d++) acc[d] *= corr;
            mx = s;
        }
        float p = __expf(s - mx);
        l += p;
        const uint32_t* vr = (const uint32_t*)(vl + j * 64);
#pragma unroll
        for (int d2 = 0; d2 < 32; d2++) {
            uint32_t u = vr[d2];
            acc[d2 * 2]     += p * bflo(u);
            acc[d2 * 2 + 1] += p * bfhi(u);
        }
    }

    if (t < NN) {
        float inv = 1.f / l;
        uint32_t* dst = (uint32_t*)(out + ((size_t)(b * NN + row)) * DD + hh * 64);
#pragma unroll
        for (int d2 = 0; d2 < 32; d2++) {
            uint32_t lo = f2bf_bits(acc[d2 * 2] * inv);
            uint32_t hi = f2bf_bits(acc[d2 * 2 + 1] * inv);
            dst[d2] = lo | (hi << 16);
        }
    }
}

// ---------------- key selection + mask: one block per image, tree reductions ----------------
__global__ __launch_bounds__(256) void select_kernel(const float* __restrict__ xq, const float* __restrict__ ke,
    const float* __restrict__ mp, int* __restrict__ idxo, float* __restrict__ masko)
{
    const int b = blockIdx.x, t = threadIdx.x;
    const int w = t >> 6, lane = t & 63;
    const float* q = xq + (size_t)b * NN * DD;   // row (b, 0)
    float q0 = q[t], q1 = q[t + 256], q2 = q[t + 512];
    __shared__ float red[21][4];
    __shared__ int bsel;
    float part[21];
    part[0] = q0 * q0 + q1 * q1 + q2 * q2;
#pragma unroll
    for (int k = 0; k < 10; k++) {
        const float* kr = ke + k * DD;
        float k0 = kr[t], k1 = kr[t + 256], k2 = kr[t + 512];
        part[1 + 2 * k] = q0 * k0 + q1 * k1 + q2 * k2;
        part[2 + 2 * k] = k0 * k0 + k1 * k1 + k2 * k2;
    }
#pragma unroll
    for (int i = 0; i < 21; i++) {
        float v = part[i];
        for (int o = 32; o > 0; o >>= 1) v += __shfl_xor(v, o);
        if (lane == 0) red[i][w] = v;
    }
    __syncthreads();
    if (t == 0) {
        float qn = sqrtf(red[0][0] + red[0][1] + red[0][2] + red[0][3]) + 1e-8f;
        float best = -1e30f; int bi = 0;
        for (int k = 0; k < 10; k++) {
            float dot = red[1 + 2 * k][0] + red[1 + 2 * k][1] + red[1 + 2 * k][2] + red[1 + 2 * k][3];
            float kn = sqrtf(red[2 + 2 * k][0] + red[2 + 2 * k][1] + red[2 + 2 * k][2] + red[2 + 2 * k][3]) + 1e-8f;
            float sim = dot / (qn * kn);         // argmin(1-sim) == argmax(sim), first-max tie rule
            if (sim > best) { best = sim; bi = k; }
        }
        idxo[b] = bi; bsel = bi;
    }
    __syncthreads();
    for (int c = t; c < NCC; c += 256) {
        float v = mp[bsel * NCC + c];
        masko[(size_t)b * NCC + c] = 2.f / (1.f + __expf(-v));
    }
}

// e_sel layout: [layer(3)][part(2)][B][20][768], fp32 -> bf16
__global__ __launch_bounds__(256) void gather_e_kernel(const float* __restrict__ ep, const int* __restrict__ idx,
                                                       bf16* __restrict__ es)
{
    int i = blockIdx.x * 256 + threadIdx.x;
    const int total = BB * 120 * 96;
    if (i >= total) return;
    int c = (i % 96) * 8;
    int rr = i / 96;
    int trow = rr % 120, b = rr / 120;
    int li = trow / 40, part = (trow / 20) % 2, tk = trow % 20;
    const float* s = ep + ((size_t)(idx[b] * 120 + trow)) * DD + c;
    *(uint4*)(es + ((size_t)(((li * 2 + part) * BB + b) * 20 + tk)) * DD + c)
        = pack8(*(const float4*)s, *(const float4*)(s + 4));
}

// gstage layout: [layer(2)][part(2)][128 rows (5 valid)][768], fp32 -> bf16
__global__ __launch_bounds__(64) void gstage_kernel(const float* __restrict__ gp, bf16* __restrict__ gs) {
    int i = blockIdx.x * 64 + threadIdx.x;
    if (i >= 20 * 96) return;
    int c = (i % 96) * 8;
    int row = i / 96;
    int li = row / 10, part = (row / 5) % 2, tk = row % 5;
    const float* s = gp + (size_t)row * DD + c;
    *(uint4*)(gs + ((size_t)((li * 2 + part) * 128 + tk)) * DD + c)
        = pack8(*(const float4*)s, *(const float4*)(s + 4));
}

// ---------------- head: logits = feat @ head_w^T + head_b, * mask (fp32 out) ----------------
__global__ __launch_bounds__(256) void head_kernel(const bf16* __restrict__ feat, const float* __restrict__ hw,
    const float* __restrict__ hb, const float* __restrict__ mask, float* __restrict__ out)
{
    int i = blockIdx.x * 256 + threadIdx.x;
    if (i >= BB * NCC) return;
    int b = i / NCC, c = i % NCC;
    const bf16*  f = feat + (size_t)b * DD;
    const float* w = hw + (size_t)c * DD;
    float s = 0.f;
    for (int d = 0; d < DD; d++) s += __bfloat162float(f[d]) * w[d];
    s += hb[c];
    out[i] = s * mask[i];
}

extern "C" void kernel_launch(void* const* d_in, const int* in_sizes, int n_in,
                              void* d_out, int out_size, void* d_ws, size_t ws_size,
                              hipStream_t stream)
{
    const float* inp       = (const float*)d_in[0];
    const float* patch_w   = (const float*)d_in[1];
    const float* patch_b   = (const float*)d_in[2];
    const float* cls_tok   = (const float*)d_in[3];
    const float* pos_emb   = (const float*)d_in[4];
    const float* ln1_s     = (const float*)d_in[5];
    const float* ln1_b     = (const float*)d_in[6];
    const float* qkv_w     = (const float*)d_in[7];
    const float* qkv_b     = (const float*)d_in[8];
    const float* proj_w    = (const float*)d_in[9];
    const float* proj_b    = (const float*)d_in[10];
    const float* ln2_s     = (const float*)d_in[11];
    const float* ln2_b     = (const float*)d_in[12];
    const float* fc1_w     = (const float*)d_in[13];
    const float* fc1_b     = (const float*)d_in[14];
    const float* fc2_w     = (const float*)d_in[15];
    const float* fc2_b     = (const float*)d_in[16];
    const float* norm_s    = (const float*)d_in[17];
    const float* norm_b    = (const float*)d_in[18];
    const float* head_w    = (const float*)d_in[19];
    const float* head_b    = (const float*)d_in[20];
    const float* key_emb   = (const float*)d_in[21];
    const float* mask_p    = (const float*)d_in[22];
    const float* g_prompts = (const float*)d_in[23];
    const float* e_prompts = (const float*)d_in[24];

    char* p = (char*)d_ws;
    auto alloc = [&](size_t bytes) { char* r = p; p += (bytes + 255) & ~(size_t)255; return r; };

    // ---- rotating JIT bf16 weight buffer (4.7 MB; converted immediately before each GEMM) ----
    bf16* wbuf = (bf16*)alloc((size_t)FFD * DD * 2);          // max weight: 3072x768

    // ---- lifetime-aliased activations (~146 MiB, same as proven baseline) ----
    float* xb  = (float*)alloc((size_t)MROWS * DD * 4);       // 38.7 MB, persistent residual
    bf16*  h   = (bf16*) alloc((size_t)MPAD * DD * 2);        // 19.5 MB, ln-out / attn-out (aliased)
    char*  QF  = (char*) alloc((size_t)MPAD * FFD * 2);       // 77.9 MB union: P+tmp | qkvb | ffb
    bf16*  e_sel = (bf16*) alloc((size_t)6 * 1280 * DD * 2);  // 11.8 MB
    bf16*  gst   = (bf16*) alloc((size_t)4 * 128 * DD * 2);
    bf16*  pkg   = (bf16*) alloc((size_t)128 * DD * 2);
    bf16*  pvg   = (bf16*) alloc((size_t)128 * DD * 2);
    bf16*  pke   = (bf16*) alloc((size_t)1280 * DD * 2);
    bf16*  pve   = (bf16*) alloc((size_t)1280 * DD * 2);
    bf16*  feat  = (bf16*) alloc((size_t)BB * DD * 2);
    float* maskf = (float*)alloc((size_t)BB * NCC * 4);
    int*   idxp  = (int*)  alloc((size_t)BB * 4);

    bf16*  qkvb = (bf16*)QF;                       // live: qkv-gemm -> attn
    bf16*  ffb  = (bf16*)QF;                       // live: fc1 -> fc2 (qkvb dead by then)
    bf16*  ato  = h;                               // attn-out aliases h (h dead after qkv gemm)

    auto cvt = [&](const float* s, size_t n) {     // fp32 -> bf16 into wbuf (stream-serialized)
        int n8 = (int)(n >> 3);
        f2b_kernel<<<(n8 + 255) / 256, 256, 0, stream>>>(s, wbuf, n8);
    };

    auto embed = [&]() {
        bf16*  P   = (bf16*)QF;                    // 19.3 MB at offset 0
        float* tmp = (float*)(QF + (size_t)20 * 1024 * 1024);  // 38.5 MB at +20 MB (disjoint)
        cvt(patch_w, (size_t)DD * DD);
        patchify_kernel<<<(NPP * BB * 96) / 256, 256, 0, stream>>>(inp, P);
        gemm_bb<false, false, true><<<dim3(98, 6), 256, 0, stream>>>(P, wbuf, patch_b, nullptr, tmp, nullptr,
                                                                     NPP * BB, DD, DD);
        assemble_x0_kernel<<<(MROWS * DD) / 256, 256, 0, stream>>>(tmp, cls_tok, pos_emb, xb);
    };

    auto layer = [&](int n, int n_extra, const bf16* pkp, const bf16* pvp, int pstride) {
        // qkv weights (2304x768) -> wbuf; also reused by the pk/pv prompt gemms below
        cvt(qkv_w + (size_t)n * 2304 * DD, (size_t)2304 * DD);
        ln_kernel<<<MROWS, 256, 0, stream>>>(xb, (long long)DD, ln1_s + n * DD, ln1_b + n * DD, h);
        gemm_bb<false, false, false><<<dim3(99, 18), 256, 0, stream>>>(
            h, wbuf, qkv_b + n * 2304, nullptr, nullptr, qkvb, MROWS, 2304, DD);
        if (n_extra == 5) {
            const bf16* gk = gst + (size_t)(n * 2 + 0) * 128 * DD;
            const bf16* gv = gst + (size_t)(n * 2 + 1) * 128 * DD;
            gemm_bb<false, false, false><<<dim3(1, 6), 256, 0, stream>>>(
                gk, wbuf + (size_t)768 * DD, qkv_b + n * 2304 + 768, nullptr, nullptr, pkg, 5, DD, DD);
            gemm_bb<false, false, false><<<dim3(1, 6), 256, 0, stream>>>(
                gv, wbuf + (size_t)1536 * DD, qkv_b + n * 2304 + 1536, nullptr, nullptr, pvg, 5, DD, DD);
        } else if (n_extra == 20) {
            int li = n - 2;
            const bf16* ek = e_sel + (size_t)(li * 2 + 0) * 1280 * DD;
            const bf16* ev = e_sel + (size_t)(li * 2 + 1) * 1280 * DD;
            gemm_bb<false, false, false><<<dim3(10, 6), 256, 0, stream>>>(
                ek, wbuf + (size_t)768 * DD, qkv_b + n * 2304 + 768, nullptr, nullptr, pke, 1280, DD, DD);
            gemm_bb<false, false, false><<<dim3(10, 6), 256, 0, stream>>>(
                ev, wbuf + (size_t)1536 * DD, qkv_b + n * 2304 + 1536, nullptr, nullptr, pve, 1280, DD, DD);
        }
        attn_kernel<<<BB * HH, 256, 0, stream>>>(qkvb, pkp, pvp, n_extra, pstride, ato);
        cvt(proj_w + (size_t)n * DD * DD, (size_t)DD * DD);
        gemm_bb<true, false, true><<<dim3(99, 6), 256, 0, stream>>>(
            ato, wbuf, proj_b + n * DD, xb, xb, nullptr, MROWS, DD, DD);
        ln_kernel<<<MROWS, 256, 0, stream>>>(xb, (long long)DD, ln2_s + n * DD, ln2_b + n * DD, h);
        cvt(fc1_w + (size_t)n * FFD * DD, (size_t)FFD * DD);
        gemm_bb<false, true, false><<<dim3(99, 24), 256, 0, stream>>>(
            h, wbuf, fc1_b + n * FFD, nullptr, nullptr, ffb, MROWS, FFD, DD);
        cvt(fc2_w + (size_t)n * DD * FFD, (size_t)DD * FFD);
        gemm_bb<true, false, true><<<dim3(99, 6), 256, 0, stream>>>(
            ffb, wbuf, fc2_b + n * DD, xb, xb, nullptr, MROWS, DD, FFD);
    };

    // 1+2) embed, then frozen query pass
    embed();
    for (int n = 0; n < LL; n++) layer(n, 0, nullptr, nullptr, 0);

    // 3) key selection, mask, prompt gathers (uses pass-1 xb; must precede re-embed)
    select_kernel<<<BB, 256, 0, stream>>>(xb, key_emb, mask_p, idxp, maskf);
    gather_e_kernel<<<(BB * 120 * 96) / 256, 256, 0, stream>>>(e_prompts, idxp, e_sel);
    gstage_kernel<<<30, 64, 0, stream>>>(g_prompts, gst);

    // 4) re-embed, then prompted pass
    embed();
    for (int n = 0; n < LL; n++) {
        if (n < 2)       layer(n, 5,  pkg, pvg, 0);
        else if (n < 5)  layer(n, 20, pke, pve, 20 * DD);
        else             layer(n, 0,  nullptr, nullptr, 0);
    }

    // 5) final norm (row 0 of each image) + head
    ln_kernel<<<BB, 256, 0, stream>>>(xb, (long long)NN * DD, norm_s, norm_b, feat);
    head_kernel<<<(BB * NCC + 255) / 256, 256, 0, stream>>>(feat, head_w, head_b, maskf, (float*)d_out);
}

// Round 5
// 14600.841 us; speedup vs baseline: 1.9299x; 1.4122x over previous
//
#include <hip/hip_runtime.h>
#include <hip/hip_bf16.h>
#include <stdint.h>

using bf16 = __hip_bfloat16;
typedef short bf16x8 __attribute__((ext_vector_type(8)));
typedef float f32x4 __attribute__((ext_vector_type(4)));

#define BB 64
#define LL 12
#define DD 768
#define HH 12
#define HDD 64
#define FFD 3072
#define NN 197
#define NPP 196
#define NCC 100
#define MROWS (BB * NN)      // 12608
#define MPAD  12672          // 99*128

__device__ __forceinline__ float bflo(uint32_t u) { return __uint_as_float(u << 16); }
__device__ __forceinline__ float bfhi(uint32_t u) { return __uint_as_float(u & 0xffff0000u); }
__device__ __forceinline__ uint32_t f2bf_bits(float f) {
    bf16 h = __float2bfloat16(f);           // RNE
    union { uint16_t u; bf16 b; } c; c.b = h;
    return (uint32_t)c.u;
}
__device__ __forceinline__ uint32_t pk2(float a, float b) { return f2bf_bits(a) | (f2bf_bits(b) << 16); }
__device__ __forceinline__ uint4 pack8(float4 a, float4 b) {
    uint4 r; r.x = pk2(a.x, a.y); r.y = pk2(a.z, a.w); r.z = pk2(b.x, b.y); r.w = pk2(b.z, b.w); return r;
}
// async global->LDS, 16B per lane; lds ptr must be wave-uniform base (+lane*16 by HW)
__device__ __forceinline__ void glds16(const void* g, void* l) {
    __builtin_amdgcn_global_load_lds((__attribute__((address_space(1))) void*)g,
                                     (__attribute__((address_space(3))) void*)l, 16, 0, 0);
}

// ---------------- fp32 -> bf16 weight conversion (RNE, identical to old in-GEMM pack8) ----------------
__global__ __launch_bounds__(256) void f2b_kernel(const float* __restrict__ s, bf16* __restrict__ d, int n8) {
    int i = blockIdx.x * 256 + threadIdx.x;
    if (i >= n8) return;
    const float4* sp = (const float4*)(s + (size_t)i * 8);
    *(uint4*)(d + (size_t)i * 8) = pack8(sp[0], sp[1]);
}

// ---------------- patchify: inputs fp32 [B,3,224,224] -> P bf16 [B*196, 768] (timm order) ----------------
__global__ __launch_bounds__(256) void patchify_kernel(const float* __restrict__ inp, bf16* __restrict__ P) {
    int i = blockIdx.x * 256 + threadIdx.x;             // 8 elements per thread
    const int total = NPP * BB * 96;
    if (i >= total) return;
    int c8 = i % 96;
    int r  = i / 96;
    int b = r / NPP, p = r % NPP;
    int ph = p / 14, pw = p % 14;
    int c = c8 * 8;
    int ch = c >> 8;
    int rem = c & 255;
    int ii = rem >> 4, jj = rem & 15;
    const float* src = inp + ((size_t)((b * 3 + ch) * 224 + ph * 16 + ii)) * 224 + pw * 16 + jj;
    float4 f0 = *(const float4*)src;
    float4 f1 = *(const float4*)(src + 4);
    *(uint4*)(P + (size_t)r * DD + c) = pack8(f0, f1);
}

// ---------------- GEMM: C[M,N] = A_bf16[M,K] @ W_bf16[N,K]^T + bias (+res)(+gelu) ----------------
// m97 structure: global_load_lds width=16 staging for A and B, 128x128 tile, BK=64, 2 barriers/K-step.
template<bool RES, bool GELU, bool OUTF32>
__global__ __launch_bounds__(256) void gemm_bb(
    const bf16* __restrict__ A, const bf16* __restrict__ W, const float* __restrict__ bias,
    const float* res, float* outf, bf16* outb, int M, int N, int K)
{
    __shared__ __align__(16) bf16 As[128 * 64];
    __shared__ __align__(16) bf16 Bs[128 * 64];
    const int t = threadIdx.x;
    const int lane = t & 63;
    const int wv = t >> 6;
    const int q15 = lane & 15, quad = lane >> 4;
    const int row0 = blockIdx.x * 128, col0 = blockIdx.y * 128;
    const int wm = (wv >> 1) * 64, wn = (wv & 1) * 64;

    f32x4 acc[4][4];
#pragma unroll
    for (int a = 0; a < 4; a++)
#pragma unroll
        for (int b2 = 0; b2 < 4; b2++) { f32x4 z = {0.f, 0.f, 0.f, 0.f}; acc[a][b2] = z; }

    const int sr = t >> 3;          // staging row within 32-row group
    const int sc = (t & 7) * 8;     // staging col (elements)
    const bf16* Ag = A + (size_t)(row0 + sr) * K + sc;
    const bf16* Wg = W + (size_t)(col0 + sr) * K + sc;
    bf16* lA = As + wv * 512;       // wave-uniform LDS base; lane i lands at +i*16B (linear order)
    bf16* lB = Bs + wv * 512;

    for (int kt = 0; kt < K; kt += 64) {
#pragma unroll
        for (int i = 0; i < 4; i++) {
            glds16(Ag + (size_t)(i * 32) * K + kt, lA + i * 2048);
            glds16(Wg + (size_t)(i * 32) * K + kt, lB + i * 2048);
        }
        __syncthreads();   // compiler drains vmcnt(0) before barrier: tile resident
#pragma unroll
        for (int k0 = 0; k0 < 64; k0 += 32) {
            bf16x8 af[4], bfv[4];
#pragma unroll
            for (int mi = 0; mi < 4; mi++)
                af[mi] = *(const bf16x8*)(As + (wm + mi * 16 + q15) * 64 + k0 + quad * 8);
#pragma unroll
            for (int ni = 0; ni < 4; ni++)
                bfv[ni] = *(const bf16x8*)(Bs + (wn + ni * 16 + q15) * 64 + k0 + quad * 8);
#pragma unroll
            for (int mi = 0; mi < 4; mi++)
#pragma unroll
                for (int ni = 0; ni < 4; ni++)
                    acc[mi][ni] = __builtin_amdgcn_mfma_f32_16x16x32_bf16(af[mi], bfv[ni], acc[mi][ni], 0, 0, 0);
        }
        __syncthreads();   // all waves done reading before next tile overwrites
    }

#pragma unroll
    for (int mi = 0; mi < 4; mi++) {
#pragma unroll
        for (int ni = 0; ni < 4; ni++) {
            const int c = col0 + wn + ni * 16 + q15;
            const float bv = bias[c];
#pragma unroll
            for (int r = 0; r < 4; r++) {
                const int row = row0 + wm + mi * 16 + quad * 4 + r;
                if (row < M) {
                    float v = acc[mi][ni][r] + bv;
                    if (RES) v += res[(size_t)row * N + c];
                    if (GELU) v = 0.5f * v * (1.0f + erff(v * 0.70710678118654752f));
                    if (OUTF32) outf[(size_t)row * N + c] = v;
                    else outb[(size_t)row * N + c] = __float2bfloat16(v);
                }
            }
        }
    }
}

// ---------------- assemble xb = concat(cls, patches) + pos (fp32 residual) ----------------
__global__ __launch_bounds__(256) void assemble_x0_kernel(const float* __restrict__ tmp,
    const float* __restrict__ cls, const float* __restrict__ pos, float* __restrict__ xb)
{
    size_t i = (size_t)blockIdx.x * 256 + threadIdx.x;
    if (i >= (size_t)MROWS * DD) return;
    int c = (int)(i % DD);
    int r = (int)(i / DD);
    int b = r / NN, tt = r % NN;
    float v;
    if (tt == 0) v = cls[c];
    else        v = tmp[(size_t)(b * NPP + tt - 1) * DD + c];
    v += pos[(size_t)tt * DD + c];
    xb[i] = v;
}

// ---------------- LayerNorm row kernel: fp32 in -> bf16 out, fp32 params ----------------
__global__ __launch_bounds__(256) void ln_kernel(const float* __restrict__ x, long long rstride,
    const float* __restrict__ sc, const float* __restrict__ bi, bf16* __restrict__ out)
{
    int r = blockIdx.x;
    const float* xr = x + (size_t)r * rstride;
    int t = threadIdx.x;
    float v0 = xr[t], v1 = xr[t + 256], v2 = xr[t + 512];
    __shared__ float r1[256], r2[256];
    r1[t] = v0 + v1 + v2;
    r2[t] = v0 * v0 + v1 * v1 + v2 * v2;
    __syncthreads();
    for (int o = 128; o > 0; o >>= 1) {
        if (t < o) { r1[t] += r1[t + o]; r2[t] += r2[t + o]; }
        __syncthreads();
    }
    float mu = r1[0] * (1.f / 768.f);
    float var = fmaxf(r2[0] * (1.f / 768.f) - mu * mu, 0.f);
    float rs = rsqrtf(var + 1e-6f);
    bf16* o_ = out + (size_t)r * DD;
    o_[t]       = __float2bfloat16((v0 - mu) * rs * sc[t]       + bi[t]);
    o_[t + 256] = __float2bfloat16((v1 - mu) * rs * sc[t + 256] + bi[t + 256]);
    o_[t + 512] = __float2bfloat16((v2 - mu) * rs * sc[t + 512] + bi[t + 512]);
}

// ---------------- MFMA flash attention: one block per (b, head); 4 waves x 64 q-rows ----------------
// swapped QK^T (mfma(K,Q) -> S^T) so row-softmax is per-lane + 2 shfl_xor; P -> bf16 via per-wave LDS.
// K rows 128 B (pow2) XOR-swizzled; V transposed into 512-B rows (pow2 -- XOR swizzle provably in-row;
// the previous 448-B row version overflowed into the next row and corrupted V: that was the r1/r3 bug).
__global__ __launch_bounds__(256) void attn_kernel(const bf16* __restrict__ qkv,
    const bf16* __restrict__ pk, const bf16* __restrict__ pv,
    int n_extra, int pstride, bf16* __restrict__ out)
{
    const int bh = blockIdx.x;
    const int b = bh / HH, hh = bh % HH;
    const int Nk = NN + n_extra;            // <= 217

    __shared__ __align__(16) bf16 kl[224 * 64];     // 28672 B, swizzled 128-B rows
    __shared__ __align__(16) bf16 vt[64 * 256];     // 32768 B, vt[d][j], swizzled 512-B rows
    __shared__ __align__(16) bf16 pl[4][64 * 32];   // 16384 B, per-wave P tile [q][jloc], stride 32
    __shared__ float srow[4][64];                   // 1024 B, per-wave rescale/inv-l broadcast
    // total 78848 B -> 2 blocks/CU

    const int t = threadIdx.x;
    const int w = t >> 6, lane = t & 63;
    const int q15 = lane & 15, quad = lane >> 4;
    char* klb = (char*)kl;
    char* vtb = (char*)vt;

    // ---- stage K rows (XOR-swizzle: byte-in-row ^= (row&7)<<4; row=128B pow2 => in-row) ----
    for (int idx = t; idx < Nk * 8; idx += 256) {
        int j = idx >> 3, c = (idx & 7) * 8;
        const bf16* ks;
        if (j < NN) ks = qkv + ((size_t)(b * NN + j)) * 2304 + 768 + hh * 64 + c;
        else        ks = pk + (size_t)(pstride ? b * pstride : 0) + (size_t)(j - NN) * DD + hh * 64 + c;
        *(uint4*)(klb + j * 128 + ((c * 2) ^ ((j & 7) << 4))) = *(const uint4*)ks;
    }
    // ---- stage V transposed: vt[d][j] (zero-padded to j<224), swizzled per d-row; 512-B rows ----
    for (int idx = t; idx < 112 * 8; idx += 256) {
        int jp = idx >> 3, c = (idx & 7) * 8;
        int j0 = jp * 2;
        uint4 va = {0, 0, 0, 0}, vb = {0, 0, 0, 0};
        if (j0 < Nk) {
            const bf16* vs;
            if (j0 < NN) vs = qkv + ((size_t)(b * NN + j0)) * 2304 + 1536 + hh * 64 + c;
            else vs = pv + (size_t)(pstride ? b * pstride : 0) + (size_t)(j0 - NN) * DD + hh * 64 + c;
            va = *(const uint4*)vs;
        }
        if (j0 + 1 < Nk) {
            int j1 = j0 + 1;
            const bf16* vs;
            if (j1 < NN) vs = qkv + ((size_t)(b * NN + j1)) * 2304 + 1536 + hh * 64 + c;
            else vs = pv + (size_t)(pstride ? b * pstride : 0) + (size_t)(j1 - NN) * DD + hh * 64 + c;
            vb = *(const uint4*)vs;
        }
        uint32_t au[4] = {va.x, va.y, va.z, va.w};
        uint32_t bu[4] = {vb.x, vb.y, vb.z, vb.w};
#pragma unroll
        for (int i = 0; i < 4; i++) {
            int d0 = c + 2 * i, d1 = d0 + 1;
            uint32_t lo = (au[i] & 0xffffu) | (bu[i] << 16);
            uint32_t hi = (au[i] >> 16) | (bu[i] & 0xffff0000u);
            *(uint32_t*)(vtb + d0 * 512 + ((4 * jp) ^ ((d0 & 7) << 4))) = lo;
            *(uint32_t*)(vtb + d1 * 512 + ((4 * jp) ^ ((d1 & 7) << 4))) = hi;
        }
    }
    __syncthreads();

    // ---- Q fragments from global (B-frag role: n=q, k=d); q rows clamped (stores guarded) ----
    bf16x8 qf[4][2];
#pragma unroll
    for (int qi = 0; qi < 4; qi++) {
        int qr = w * 64 + qi * 16 + q15;
        if (qr > NN - 1) qr = NN - 1;
        const bf16* qs = qkv + (size_t)(b * NN + qr) * 2304 + hh * 64;
#pragma unroll
        for (int kk = 0; kk < 2; kk++)
            qf[qi][kk] = *(const bf16x8*)(qs + kk * 32 + quad * 8);
    }

    f32x4 oc[4][4];
#pragma unroll
    for (int a = 0; a < 4; a++)
#pragma unroll
        for (int b2 = 0; b2 < 4; b2++) { f32x4 z = {0.f, 0.f, 0.f, 0.f}; oc[a][b2] = z; }
    float mrun[4] = {-3e38f, -3e38f, -3e38f, -3e38f};
    float lrun[4] = {0.f, 0.f, 0.f, 0.f};

    bf16* plw = pl[w];
    uint32_t* plu = (uint32_t*)plw;
    const int swz = (q15 & 7) << 4;   // rows jc+q15, jc+16+q15 have (row&7) == (q15&7)

    for (int jc = 0; jc < Nk; jc += 32) {
        // S^T chunk: C[j][q] = sum_d K[j][d] Q[q][d]
        f32x4 st[2][4];
#pragma unroll
        for (int ji = 0; ji < 2; ji++)
#pragma unroll
            for (int qi = 0; qi < 4; qi++) { f32x4 z = {0.f, 0.f, 0.f, 0.f}; st[ji][qi] = z; }
#pragma unroll
        for (int kk = 0; kk < 2; kk++) {
            bf16x8 kf0 = *(const bf16x8*)(klb + (jc + q15) * 128 + ((kk * 64 + quad * 16) ^ swz));
            bf16x8 kf1 = *(const bf16x8*)(klb + (jc + 16 + q15) * 128 + ((kk * 64 + quad * 16) ^ swz));
#pragma unroll
            for (int qi = 0; qi < 4; qi++) {
                st[0][qi] = __builtin_amdgcn_mfma_f32_16x16x32_bf16(kf0, qf[qi][kk], st[0][qi], 0, 0, 0);
                st[1][qi] = __builtin_amdgcn_mfma_f32_16x16x32_bf16(kf1, qf[qi][kk], st[1][qi], 0, 0, 0);
            }
        }
        // online softmax per q (value at j = jc + ji*16 + quad*4 + r, q = qi*16 + q15)
#pragma unroll
        for (int qi = 0; qi < 4; qi++) {
            float s[8];
#pragma unroll
            for (int ji = 0; ji < 2; ji++)
#pragma unroll
                for (int r = 0; r < 4; r++) {
                    int j = jc + ji * 16 + quad * 4 + r;
                    float v = st[ji][qi][r] * 0.125f;
                    s[ji * 4 + r] = (j < Nk) ? v : -3e38f;
                }
            float mx = s[0];
#pragma unroll
            for (int i = 1; i < 8; i++) mx = fmaxf(mx, s[i]);
            mx = fmaxf(mx, __shfl_xor(mx, 16));
            mx = fmaxf(mx, __shfl_xor(mx, 32));
            float mn = fmaxf(mrun[qi], mx);
            float scl = __expf(mrun[qi] - mn);    // 0 on first chunk (-inf arg)
            uint32_t pb[8];
            float ps = 0.f;
#pragma unroll
            for (int i = 0; i < 8; i++) {
                pb[i] = f2bf_bits(__expf(s[i] - mn));
                ps += bflo(pb[i]);               // denominator = sum of the bf16-rounded P actually used
            }
            ps += __shfl_xor(ps, 16);
            ps += __shfl_xor(ps, 32);
            lrun[qi] = lrun[qi] * scl + ps;
            mrun[qi] = mn;
            // write P (bf16) to per-wave tile: pl[q][jloc], jloc = ji*16 + quad*4 + r
            int qrow = qi * 16 + q15;
            uint32_t* pd = plu + qrow * 16 + quad * 2;
            pd[0] = pb[0] | (pb[1] << 16);
            pd[1] = pb[2] | (pb[3] << 16);
            pd[8] = pb[4] | (pb[5] << 16);
            pd[9] = pb[6] | (pb[7] << 16);
            if (quad == 0) srow[w][qrow] = scl;
        }
        asm volatile("s_waitcnt lgkmcnt(0)" ::: "memory");  // wave's LDS writes visible cross-lane
        // rescale O (O rows live at quad*4+r, scale was computed at q15 lanes -> via srow)
#pragma unroll
        for (int mi = 0; mi < 4; mi++)
#pragma unroll
            for (int r = 0; r < 4; r++) {
                float sc = srow[w][mi * 16 + quad * 4 + r];
#pragma unroll
                for (int ni = 0; ni < 4; ni++) oc[mi][ni][r] *= sc;
            }
        // PV: C[q][d] += P[q][jloc] * vt[d][jloc]
        bf16x8 vf[4];
#pragma unroll
        for (int ni = 0; ni < 4; ni++) {
            int d = ni * 16 + q15;
            vf[ni] = *(const bf16x8*)(vtb + d * 512 + ((jc * 2 + quad * 16) ^ ((d & 7) << 4)));
        }
#pragma unroll
        for (int mi = 0; mi < 4; mi++) {
            bf16x8 paf = *(const bf16x8*)(plw + (mi * 16 + q15) * 32 + quad * 8);
#pragma unroll
            for (int ni = 0; ni < 4; ni++)
                oc[mi][ni] = __builtin_amdgcn_mfma_f32_16x16x32_bf16(paf, vf[ni], oc[mi][ni], 0, 0, 0);
        }
    }

    // epilogue: O / l, store
#pragma unroll
    for (int qi = 0; qi < 4; qi++)
        if (quad == 0) srow[w][qi * 16 + q15] = 1.f / lrun[qi];
    asm volatile("s_waitcnt lgkmcnt(0)" ::: "memory");
#pragma unroll
    for (int mi = 0; mi < 4; mi++)
#pragma unroll
        for (int r = 0; r < 4; r++) {
            int qg = w * 64 + mi * 16 + quad * 4 + r;
            if (qg < NN) {
                float inv = srow[w][mi * 16 + quad * 4 + r];
                bf16* dst = out + ((size_t)(b * NN + qg)) * DD + hh * 64 + q15;
#pragma unroll
                for (int ni = 0; ni < 4; ni++)
                    dst[ni * 16] = __float2bfloat16(oc[mi][ni][r] * inv);
            }
        }
}

// ---------------- key selection + mask: one block per image, tree reductions ----------------
__global__ __launch_bounds__(256) void select_kernel(const float* __restrict__ xq, const float* __restrict__ ke,
    const float* __restrict__ mp, int* __restrict__ idxo, float* __restrict__ masko)
{
    const int b = blockIdx.x, t = threadIdx.x;
    const int w = t >> 6, lane = t & 63;
    const float* q = xq + (size_t)b * NN * DD;   // row (b, 0)
    float q0 = q[t], q1 = q[t + 256], q2 = q[t + 512];
    __shared__ float red[21][4];
    __shared__ int bsel;
    float part[21];
    part[0] = q0 * q0 + q1 * q1 + q2 * q2;
#pragma unroll
    for (int k = 0; k < 10; k++) {
        const float* kr = ke + k * DD;
        float k0 = kr[t], k1 = kr[t + 256], k2 = kr[t + 512];
        part[1 + 2 * k] = q0 * k0 + q1 * k1 + q2 * k2;
        part[2 + 2 * k] = k0 * k0 + k1 * k1 + k2 * k2;
    }
#pragma unroll
    for (int i = 0; i < 21; i++) {
        float v = part[i];
        for (int o = 32; o > 0; o >>= 1) v += __shfl_xor(v, o);
        if (lane == 0) red[i][w] = v;
    }
    __syncthreads();
    if (t == 0) {
        float qn = sqrtf(red[0][0] + red[0][1] + red[0][2] + red[0][3]) + 1e-8f;
        float best = -1e30f; int bi = 0;
        for (int k = 0; k < 10; k++) {
            float dot = red[1 + 2 * k][0] + red[1 + 2 * k][1] + red[1 + 2 * k][2] + red[1 + 2 * k][3];
            float kn = sqrtf(red[2 + 2 * k][0] + red[2 + 2 * k][1] + red[2 + 2 * k][2] + red[2 + 2 * k][3]) + 1e-8f;
            float sim = dot / (qn * kn);         // argmin(1-sim) == argmax(sim), first-max tie rule
            if (sim > best) { best = sim; bi = k; }
        }
        idxo[b] = bi; bsel = bi;
    }
    __syncthreads();
    for (int c = t; c < NCC; c += 256) {
        float v = mp[bsel * NCC + c];
        masko[(size_t)b * NCC + c] = 2.f / (1.f + __expf(-v));
    }
}

// e_sel layout: [layer(3)][part(2)][B][20][768], fp32 -> bf16
__global__ __launch_bounds__(256) void gather_e_kernel(const float* __restrict__ ep, const int* __restrict__ idx,
                                                       bf16* __restrict__ es)
{
    int i = blockIdx.x * 256 + threadIdx.x;
    const int total = BB * 120 * 96;
    if (i >= total) return;
    int c = (i % 96) * 8;
    int rr = i / 96;
    int trow = rr % 120, b = rr / 120;
    int li = trow / 40, part = (trow / 20) % 2, tk = trow % 20;
    const float* s = ep + ((size_t)(idx[b] * 120 + trow)) * DD + c;
    *(uint4*)(es + ((size_t)(((li * 2 + part) * BB + b) * 20 + tk)) * DD + c)
        = pack8(*(const float4*)s, *(const float4*)(s + 4));
}

// gstage layout: [layer(2)][part(2)][128 rows (5 valid)][768], fp32 -> bf16
__global__ __launch_bounds__(64) void gstage_kernel(const float* __restrict__ gp, bf16* __restrict__ gs) {
    int i = blockIdx.x * 64 + threadIdx.x;
    if (i >= 20 * 96) return;
    int c = (i % 96) * 8;
    int row = i / 96;
    int li = row / 10, part = (row / 5) % 2, tk = row % 5;
    const float* s = gp + (size_t)row * DD + c;
    *(uint4*)(gs + ((size_t)((li * 2 + part) * 128 + tk)) * DD + c)
        = pack8(*(const float4*)s, *(const float4*)(s + 4));
}

// ---------------- head: logits = feat @ head_w^T + head_b, * mask (fp32 out) ----------------
__global__ __launch_bounds__(256) void head_kernel(const bf16* __restrict__ feat, const float* __restrict__ hw,
    const float* __restrict__ hb, const float* __restrict__ mask, float* __restrict__ out)
{
    int i = blockIdx.x * 256 + threadIdx.x;
    if (i >= BB * NCC) return;
    int b = i / NCC, c = i % NCC;
    const bf16*  f = feat + (size_t)b * DD;
    const float* w = hw + (size_t)c * DD;
    float s = 0.f;
    for (int d = 0; d < DD; d++) s += __bfloat162float(f[d]) * w[d];
    s += hb[c];
    out[i] = s * mask[i];
}

extern "C" void kernel_launch(void* const* d_in, const int* in_sizes, int n_in,
                              void* d_out, int out_size, void* d_ws, size_t ws_size,
                              hipStream_t stream)
{
    const float* inp       = (const float*)d_in[0];
    const float* patch_w   = (const float*)d_in[1];
    const float* patch_b   = (const float*)d_in[2];
    const float* cls_tok   = (const float*)d_in[3];
    const float* pos_emb   = (const float*)d_in[4];
    const float* ln1_s     = (const float*)d_in[5];
    const float* ln1_b     = (const float*)d_in[6];
    const float* qkv_w     = (const float*)d_in[7];
    const float* qkv_b     = (const float*)d_in[8];
    const float* proj_w    = (const float*)d_in[9];
    const float* proj_b    = (const float*)d_in[10];
    const float* ln2_s     = (const float*)d_in[11];
    const float* ln2_b     = (const float*)d_in[12];
    const float* fc1_w     = (const float*)d_in[13];
    const float* fc1_b     = (const float*)d_in[14];
    const float* fc2_w     = (const float*)d_in[15];
    const float* fc2_b     = (const float*)d_in[16];
    const float* norm_s    = (const float*)d_in[17];
    const float* norm_b    = (const float*)d_in[18];
    const float* head_w    = (const float*)d_in[19];
    const float* head_b    = (const float*)d_in[20];
    const float* key_emb   = (const float*)d_in[21];
    const float* mask_p    = (const float*)d_in[22];
    const float* g_prompts = (const float*)d_in[23];
    const float* e_prompts = (const float*)d_in[24];

    char* p = (char*)d_ws;
    auto alloc = [&](size_t bytes) { char* r = p; p += (bytes + 255) & ~(size_t)255; return r; };

    // ---- rotating JIT bf16 weight buffer (4.7 MB; converted immediately before each GEMM) ----
    bf16* wbuf = (bf16*)alloc((size_t)FFD * DD * 2);          // max weight: 3072x768

    // ---- lifetime-aliased activations (~146 MiB, same as proven baseline) ----
    float* xb  = (float*)alloc((size_t)MROWS * DD * 4);       // 38.7 MB, persistent residual
    bf16*  h   = (bf16*) alloc((size_t)MPAD * DD * 2);        // 19.5 MB, ln-out / attn-out (aliased)
    char*  QF  = (char*) alloc((size_t)MPAD * FFD * 2);       // 77.9 MB union: P+tmp | qkvb | ffb
    bf16*  e_sel = (bf16*) alloc((size_t)6 * 1280 * DD * 2);  // 11.8 MB
    bf16*  gst   = (bf16*) alloc((size_t)4 * 128 * DD * 2);
    bf16*  pkg   = (bf16*) alloc((size_t)128 * DD * 2);
    bf16*  pvg   = (bf16*) alloc((size_t)128 * DD * 2);
    bf16*  pke   = (bf16*) alloc((size_t)1280 * DD * 2);
    bf16*  pve   = (bf16*) alloc((size_t)1280 * DD * 2);
    bf16*  feat  = (bf16*) alloc((size_t)BB * DD * 2);
    float* maskf = (float*)alloc((size_t)BB * NCC * 4);
    int*   idxp  = (int*)  alloc((size_t)BB * 4);

    bf16*  qkvb = (bf16*)QF;                       // live: qkv-gemm -> attn
    bf16*  ffb  = (bf16*)QF;                       // live: fc1 -> fc2 (qkvb dead by then)
    bf16*  ato  = h;                               // attn-out aliases h (h dead after qkv gemm)

    auto cvt = [&](const float* s, size_t n) {     // fp32 -> bf16 into wbuf (stream-serialized)
        int n8 = (int)(n >> 3);
        f2b_kernel<<<(n8 + 255) / 256, 256, 0, stream>>>(s, wbuf, n8);
    };

    auto embed = [&]() {
        bf16*  P   = (bf16*)QF;                    // 19.3 MB at offset 0
        float* tmp = (float*)(QF + (size_t)20 * 1024 * 1024);  // 38.5 MB at +20 MB (disjoint)
        cvt(patch_w, (size_t)DD * DD);
        patchify_kernel<<<(NPP * BB * 96) / 256, 256, 0, stream>>>(inp, P);
        gemm_bb<false, false, true><<<dim3(98, 6), 256, 0, stream>>>(P, wbuf, patch_b, nullptr, tmp, nullptr,
                                                                     NPP * BB, DD, DD);
        assemble_x0_kernel<<<(MROWS * DD) / 256, 256, 0, stream>>>(tmp, cls_tok, pos_emb, xb);
    };

    auto layer = [&](int n, int n_extra, const bf16* pkp, const bf16* pvp, int pstride) {
        // qkv weights (2304x768) -> wbuf; also reused by the pk/pv prompt gemms below
        cvt(qkv_w + (size_t)n * 2304 * DD, (size_t)2304 * DD);
        ln_kernel<<<MROWS, 256, 0, stream>>>(xb, (long long)DD, ln1_s + n * DD, ln1_b + n * DD, h);
        gemm_bb<false, false, false><<<dim3(99, 18), 256, 0, stream>>>(
            h, wbuf, qkv_b + n * 2304, nullptr, nullptr, qkvb, MROWS, 2304, DD);
        if (n_extra == 5) {
            const bf16* gk = gst + (size_t)(n * 2 + 0) * 128 * DD;
            const bf16* gv = gst + (size_t)(n * 2 + 1) * 128 * DD;
            gemm_bb<false, false, false><<<dim3(1, 6), 256, 0, stream>>>(
                gk, wbuf + (size_t)768 * DD, qkv_b + n * 2304 + 768, nullptr, nullptr, pkg, 5, DD, DD);
            gemm_bb<false, false, false><<<dim3(1, 6), 256, 0, stream>>>(
                gv, wbuf + (size_t)1536 * DD, qkv_b + n * 2304 + 1536, nullptr, nullptr, pvg, 5, DD, DD);
        } else if (n_extra == 20) {
            int li = n - 2;
            const bf16* ek = e_sel + (size_t)(li * 2 + 0) * 1280 * DD;
            const bf16* ev = e_sel + (size_t)(li * 2 + 1) * 1280 * DD;
            gemm_bb<false, false, false><<<dim3(10, 6), 256, 0, stream>>>(
                ek, wbuf + (size_t)768 * DD, qkv_b + n * 2304 + 768, nullptr, nullptr, pke, 1280, DD, DD);
            gemm_bb<false, false, false><<<dim3(10, 6), 256, 0, stream>>>(
                ev, wbuf + (size_t)1536 * DD, qkv_b + n * 2304 + 1536, nullptr, nullptr, pve, 1280, DD, DD);
        }
        attn_kernel<<<BB * HH, 256, 0, stream>>>(qkvb, pkp, pvp, n_extra, pstride, ato);
        cvt(proj_w + (size_t)n * DD * DD, (size_t)DD * DD);
        gemm_bb<true, false, true><<<dim3(99, 6), 256, 0, stream>>>(
            ato, wbuf, proj_b + n * DD, xb, xb, nullptr, MROWS, DD, DD);
        ln_kernel<<<MROWS, 256, 0, stream>>>(xb, (long long)DD, ln2_s + n * DD, ln2_b + n * DD, h);
        cvt(fc1_w + (size_t)n * FFD * DD, (size_t)FFD * DD);
        gemm_bb<false, true, false><<<dim3(99, 24), 256, 0, stream>>>(
            h, wbuf, fc1_b + n * FFD, nullptr, nullptr, ffb, MROWS, FFD, DD);
        cvt(fc2_w + (size_t)n * DD * FFD, (size_t)DD * FFD);
        gemm_bb<true, false, true><<<dim3(99, 6), 256, 0, stream>>>(
            ffb, wbuf, fc2_b + n * DD, xb, xb, nullptr, MROWS, DD, FFD);
    };

    // 1+2) embed, then frozen query pass
    embed();
    for (int n = 0; n < LL; n++) layer(n, 0, nullptr, nullptr, 0);

    // 3) key selection, mask, prompt gathers (uses pass-1 xb; must precede re-embed)
    select_kernel<<<BB, 256, 0, stream>>>(xb, key_emb, mask_p, idxp, maskf);
    gather_e_kernel<<<(BB * 120 * 96) / 256, 256, 0, stream>>>(e_prompts, idxp, e_sel);
    gstage_kernel<<<30, 64, 0, stream>>>(g_prompts, gst);

    // 4) re-embed, then prompted pass
    embed();
    for (int n = 0; n < LL; n++) {
        if (n < 2)       layer(n, 5,  pkg, pvg, 0);
        else if (n < 5)  layer(n, 20, pke, pve, 20 * DD);
        else             layer(n, 0,  nullptr, nullptr, 0);
    }

    // 5) final norm (row 0 of each image) + head
    ln_kernel<<<BB, 256, 0, stream>>>(xb, (long long)NN * DD, norm_s, norm_b, feat);
    head_kernel<<<(BB * NCC + 255) / 256, 256, 0, stream>>>(feat, head_w, head_b, maskf, (float*)d_out);
}